// Round 3
// baseline (85.233 us; speedup 1.0000x reference)
//
#include <hip/hip_runtime.h>
#include <math.h>

#define NPTS   4096
#define NB     8
#define IGRP   128                         // i-points per block (64 lanes x IT=2)
#define NWAVES 16
#define BLK    (NWAVES * 64)               // 1024 threads
#define JCHUNK (NPTS / NWAVES)             // 256
#define INV_H2 (1.0f / (0.03f * 0.03f))
#define INFD   3.0e38f

__device__ __forceinline__ float med3f(float a, float b, float c) {
#if defined(__has_builtin)
#if __has_builtin(__builtin_amdgcn_fmed3f)
  return __builtin_amdgcn_fmed3f(a, b, c);
#else
  return fminf(c, fmaxf(a, b));
#endif
#else
  return fminf(c, fmaxf(a, b));
#endif
}

// One broadcast ds_read_b128 feeds TWO i-points per lane (8 B LDS / pair).
// Per pair: 4 VALU dist (GEMM form, premultiplied -2*p_i) + 4 VALU ladder.
template <bool CHECK>
__device__ __forceinline__ void scan_range(
    const float4* __restrict__ sP, int lo, int hi, int i0, int i1,
    float mx0, float my0, float mz0, float sq0,
    float mx1, float my1, float mz1, float sq1,
    float& a0, float& a1, float& a2, float& a3,
    float& b0, float& b1, float& b2, float& b3) {
#pragma unroll 8
  for (int j = lo; j < hi; ++j) {
    float4 q = sP[j];                       // wave-uniform addr -> broadcast
    float u = fmaf(mz0, q.z, q.w);          // q.w = ||p_j||^2
    u = fmaf(my0, q.y, u);
    u = fmaf(mx0, q.x, u);
    float d0 = u + sq0;
    float v = fmaf(mz1, q.z, q.w);
    v = fmaf(my1, q.y, v);
    v = fmaf(mx1, q.x, v);
    float d1 = v + sq1;
    if (CHECK) {
      d0 = (j == i0) ? INFD : d0;
      d1 = (j == i1) ? INFD : d1;
    }
    a3 = med3f(a2, d0, a3); a2 = med3f(a1, d0, a2);
    a1 = med3f(a0, d0, a1); a0 = fminf(a0, d0);
    b3 = med3f(b2, d1, b3); b2 = med3f(b1, d1, b2);
    b1 = med3f(b0, d1, b1); b0 = fminf(b0, d1);
  }
}

// lowest-4 (ascending) of two ascending 4-lists: bitonic min-ladder + sort4.
__device__ __forceinline__ float4 merge4(float4 A, float4 B) {
  float L0 = fminf(A.x, B.w), L1 = fminf(A.y, B.z);
  float L2 = fminf(A.z, B.y), L3 = fminf(A.w, B.x);
  float e0 = fminf(L0, L2), e2 = fmaxf(L0, L2);
  float e1 = fminf(L1, L3), e3 = fmaxf(L1, L3);
  return make_float4(fminf(e0, e1), fmaxf(e0, e1), fminf(e2, e3), fmaxf(e2, e3));
}

__global__ __launch_bounds__(BLK)
void repulsion_kernel(const float* __restrict__ pc, float* __restrict__ out) {
  __shared__ float4 sP[NPTS];                 // 64 KB: x,y,z,||p||^2
  __shared__ float4 cand[NWAVES * IGRP];      // 32 KB

  const int blk  = blockIdx.x;
  const int b    = blk >> 5;                  // / (NPTS/IGRP)
  const int g    = blk & 31;                  // i-group within batch
  const int tid  = threadIdx.x;
  const float4* pcv = (const float4*)(pc + (size_t)b * NPTS * 3);

  // Stage batch into LDS: each thread unpacks 3 float4 -> 4 points (+ sq).
  {
    int k = tid;                              // 1024 threads cover 1024 triplets
    float4 a = pcv[3 * k + 0];
    float4 c = pcv[3 * k + 1];
    float4 e = pcv[3 * k + 2];
    float x0 = a.x, y0 = a.y, z0 = a.z;
    float x1 = a.w, y1 = c.x, z1 = c.y;
    float x2 = c.z, y2 = c.w, z2 = e.x;
    float x3 = e.y, y3 = e.z, z3 = e.w;
    sP[4 * k + 0] = make_float4(x0, y0, z0, fmaf(x0, x0, fmaf(y0, y0, z0 * z0)));
    sP[4 * k + 1] = make_float4(x1, y1, z1, fmaf(x1, x1, fmaf(y1, y1, z1 * z1)));
    sP[4 * k + 2] = make_float4(x2, y2, z2, fmaf(x2, x2, fmaf(y2, y2, z2 * z2)));
    sP[4 * k + 3] = make_float4(x3, y3, z3, fmaf(x3, x3, fmaf(y3, y3, z3 * z3)));
  }
  __syncthreads();

  const int w    = tid >> 6;                  // wave index = j-chunk
  const int lane = tid & 63;
  const int i0   = g * IGRP + lane;           // this lane's two i-points
  const int i1   = i0 + 64;

  float4 p0 = sP[i0];
  float4 p1 = sP[i1];
  const float mx0 = -2.0f * p0.x, my0 = -2.0f * p0.y, mz0 = -2.0f * p0.z, sq0 = p0.w;
  const float mx1 = -2.0f * p1.x, my1 = -2.0f * p1.y, mz1 = -2.0f * p1.z, sq1 = p1.w;

  float a0 = INFD, a1 = INFD, a2 = INFD, a3 = INFD;
  float b0 = INFD, b1 = INFD, b2 = INFD, b3 = INFD;

  const int j0 = w * JCHUNK;
  const int selfwave = g >> 1;                // [g*128, g*128+128) sits in this chunk
  if (w == selfwave) {
    const int s0 = g * IGRP;                  // 128-aligned within the 256-chunk
    scan_range<false>(sP, j0, s0, i0, i1, mx0, my0, mz0, sq0, mx1, my1, mz1, sq1,
                      a0, a1, a2, a3, b0, b1, b2, b3);
    scan_range<true >(sP, s0, s0 + IGRP, i0, i1, mx0, my0, mz0, sq0, mx1, my1, mz1, sq1,
                      a0, a1, a2, a3, b0, b1, b2, b3);
    scan_range<false>(sP, s0 + IGRP, j0 + JCHUNK, i0, i1, mx0, my0, mz0, sq0, mx1, my1, mz1, sq1,
                      a0, a1, a2, a3, b0, b1, b2, b3);
  } else {
    scan_range<false>(sP, j0, j0 + JCHUNK, i0, i1, mx0, my0, mz0, sq0, mx1, my1, mz1, sq1,
                      a0, a1, a2, a3, b0, b1, b2, b3);
  }

  cand[w * IGRP + lane]      = make_float4(a0, a1, a2, a3);
  cand[w * IGRP + 64 + lane] = make_float4(b0, b1, b2, b3);
  __syncthreads();

  // Merge 16 sorted 4-lists per i-point; threads 0..127 handle one i-point each.
  if (tid < IGRP) {
    float4 L[NWAVES];
#pragma unroll
    for (int ww = 0; ww < NWAVES; ++ww) L[ww] = cand[ww * IGRP + tid];
#pragma unroll
    for (int ww = 0; ww < 8; ++ww) L[ww] = merge4(L[2 * ww], L[2 * ww + 1]);
#pragma unroll
    for (int ww = 0; ww < 4; ++ww) L[ww] = merge4(L[2 * ww], L[2 * ww + 1]);
    float4 U = merge4(L[0], L[1]);
    float4 V = merge4(L[2], L[3]);
    // final 4-smallest set of two sorted lists (no sort needed)
    float m0 = fminf(U.x, V.w);
    float m1 = fminf(U.y, V.z);
    float m2 = fminf(U.z, V.y);
    float m3 = fminf(U.w, V.x);

    float s = 0.0f;
    s -= m0 * expf(-m0 * INV_H2);
    s -= m1 * expf(-m1 * INV_H2);
    s -= m2 * expf(-m2 * INV_H2);
    s -= m3 * expf(-m3 * INV_H2);

    for (int off = 32; off > 0; off >>= 1) s += __shfl_down(s, off);
    if ((tid & 63) == 0) atomicAdd(out, s);   // waves 0 and 1 -> 2 atomics/block
  }
}

extern "C" void kernel_launch(void* const* d_in, const int* in_sizes, int n_in,
                              void* d_out, int out_size, void* d_ws, size_t ws_size,
                              hipStream_t stream) {
  const float* pc = (const float*)d_in[0];
  float* out = (float*)d_out;
  hipMemsetAsync(out, 0, sizeof(float), stream);
  repulsion_kernel<<<dim3(NB * (NPTS / IGRP)), dim3(BLK), 0, stream>>>(pc, out);
}